// Round 5
// baseline (1076.846 us; speedup 1.0000x reference)
//
#include <hip/hip_runtime.h>

// SLAYER SNN forward, round 5.
// - time-major [t][b][c][h][w].
// - conv_tm4: odd LDS row strides, per-dx SGPR weight slices, NPX-pixel register
//   window; L5 now NCO=24/z=1 (tile staged once, half the waves/ds_reads).
// - ppp4_tm: fused psp->pool->psp with FOUR lanes per pooled neuron (one input
//   IIR each, shfl_xor combine) -> 4x parallelism + perfectly coalesced reads.
//   Sum of 0/1 spikes and 11*sum are exact in fp32, so order is irrelevant.
// - dense7s: ballot-sparse accumulation over 0/1 spike inputs (bit-exact skip
//   of zero terms, ascending-k order preserved). Kills the 2.9 GB L2 W-traffic.
// All fp32; IIR op ordering bit-matches the reference scan.

#define TT 300

#define A1 0.9048374180359595f   // exp(-1/10)
#define C1 0.2718281828459045f   // e/10
#define A2 0.36787944117144233f  // exp(-1)
#define C2 2.718281828459045f    // e
#define KREF (20.0f * C2)
#define THETA_F 10.0f

struct IIR {
  float p1, q1, p2, q2;
  __device__ IIR() : p1(0.f), q1(0.f), p2(0.f), q2(0.f) {}
  __device__ inline float step(float xin) {
    q1 = A1 * q1 + A1 * p1;
    float y = C1 * q1;
    p1 = A1 * p1 + xin;
    q2 = A2 * q2 + A2 * p2;
    float u = y - KREF * q2;
    float s = (u >= THETA_F) ? 1.0f : 0.0f;
    p2 = A2 * p2 + s;
    return s;
  }
};

// ---------------- generic tiled transpose: in[R][C] -> out[C][R] ----------------
__global__ __launch_bounds__(256) void transpose_rc(const float* __restrict__ in,
                                                    float* __restrict__ out,
                                                    int R, int C) {
  __shared__ float tile[64][65];
  int c0 = blockIdx.x * 64, r0 = blockIdx.y * 64;
  int tx = threadIdx.x & 63, ty = threadIdx.x >> 6;
  for (int i = ty; i < 64; i += 4) {
    int r = r0 + i, c = c0 + tx;
    if (r < R && c < C) tile[i][tx] = in[(long)r * C + c];
  }
  __syncthreads();
  for (int i = ty; i < 64; i += 4) {
    int c = c0 + i, r = r0 + tx;
    if (c < C && r < R) out[(long)c * R + r] = tile[tx][i];
  }
}

// ---------------- conv-weight transposes, one launch ----------------
__global__ __launch_bounds__(256) void prep_w(const float* __restrict__ Wc1,
                                              const float* __restrict__ Wc2,
                                              const float* __restrict__ Wc3,
                                              float* __restrict__ Wt1,
                                              float* __restrict__ Wt2,
                                              float* __restrict__ Wt3) {
  int i = blockIdx.x * 256 + threadIdx.x;
  if (i < 1200) { int co = i / 50, k = i % 50; Wt1[k * 24 + co] = Wc1[i]; return; }
  i -= 1200;
  if (i < 10368) { int co = i / 216, k = i % 216; Wt2[k * 48 + co] = Wc2[i]; return; }
  i -= 10368;
  if (i < 41472) { int co = i / 432, k = i % 432; Wt3[k * 96 + co] = Wc3[i]; }
}

// ---------------- per-timestep conv, time-major ----------------
// S: [T][B][CIN][HW][HW], Wt: [CIN][KS][KS][CO], U: [T][B][CO][HW][HW]
// 4 waves/block; wave w -> channels [z*4*NCO + w*NCO, +NCO); lane -> (y, x-group).
template <int CIN, int HW, int KS, int PAD, int CO, int NCO, int NPX, int RS, int NITER>
__global__ __launch_bounds__(256) void conv_tm4(const float* __restrict__ S,
                                                const float* __restrict__ Wt,
                                                float* __restrict__ U) {
  constexpr int PH = HW + 2 * PAD;
  constexpr int TILE = CIN * PH * RS;
  constexpr int XG = (HW + NPX - 1) / NPX;
  constexpr int SLOTS = HW * XG;
  constexpr int WIN = NPX + KS - 1;
  __shared__ float lin[TILE + WIN];
  const int t = blockIdx.x, b = blockIdx.y, B = gridDim.y;

  for (int i = threadIdx.x; i < TILE + WIN; i += 256) lin[i] = 0.f;
  __syncthreads();
  const float* src = S + ((long)t * B + b) * (CIN * HW * HW);
  for (int i = threadIdx.x; i < CIN * HW * HW; i += 256) {
    int ci = i / (HW * HW), r = i % (HW * HW);
    int iy = r / HW, ix = r % HW;
    lin[ci * PH * RS + (iy + PAD) * RS + ix + PAD] = src[i];
  }
  __syncthreads();

  const int lane = threadIdx.x & 63;
  const int co0 = blockIdx.z * (4 * NCO) +
                  __builtin_amdgcn_readfirstlane(threadIdx.x >> 6) * NCO;
  const float* wb = Wt + co0;

  for (int it = 0; it < NITER; ++it) {
    int slot = lane + 64 * it;
    bool act = slot < SLOTS;
    int ss = act ? slot : 0;
    int y = ss / XG, x0 = (ss % XG) * NPX;
    const float* base = lin + y * RS + x0;
    float acc[NCO][NPX];
#pragma unroll
    for (int j = 0; j < NCO; ++j)
#pragma unroll
      for (int px = 0; px < NPX; ++px) acc[j][px] = 0.f;

    for (int ci = 0; ci < CIN; ++ci) {
      const float* bp = base + ci * (PH * RS);
#pragma unroll
      for (int dy = 0; dy < KS; ++dy) {
        float win[WIN];
#pragma unroll
        for (int k = 0; k < WIN; ++k) win[k] = bp[dy * RS + k];
#pragma unroll
        for (int dx = 0; dx < KS; ++dx) {
          float wv[NCO];
#pragma unroll
          for (int j = 0; j < NCO; ++j)
            wv[j] = wb[(((ci * KS + dy) * KS + dx) * CO) + j];
#pragma unroll
          for (int px = 0; px < NPX; ++px)
#pragma unroll
            for (int j = 0; j < NCO; ++j)
              acc[j][px] += wv[j] * win[px + dx];
        }
      }
    }
    if (act) {
      float* up = U + (((long)t * B + b) * CO + co0) * (HW * HW) + y * HW + x0;
#pragma unroll
      for (int j = 0; j < NCO; ++j)
#pragma unroll
        for (int px = 0; px < NPX; ++px)
          if (x0 + px < HW) up[j * (HW * HW) + px] = acc[j][px];
    }
  }
}

// ---------------- fused psp+spike -> pool(2x2, x11) -> psp+spike, 4 lanes/neuron ----------------
// U: [T][B][C][HIN][HIN]; out: [T][B][C][HOUT][HOUT]. Thread group of 4 = one
// pooled neuron; lane sub owns input (dy=sub>>1, dx=sub&1). Spike sums are
// exact small ints so shfl combine order is exact.
template <int C, int HIN, int HOUT>
__global__ __launch_bounds__(256) void ppp4_tm(const float* __restrict__ U,
                                               float* __restrict__ out, int B) {
  const int NOUT = B * C * HOUT * HOUT;
  const long SIN = (long)B * C * HIN * HIN;
  int id = blockIdx.x * 256 + threadIdx.x;
  int sub = id & 3, m = id >> 2;
  bool active = m < NOUT;
  int mm = active ? m : 0;
  int x2 = mm % HOUT;
  int y2 = (mm / HOUT) % HOUT;
  int c = (mm / (HOUT * HOUT)) % C;
  int b = mm / (C * HOUT * HOUT);
  int iy = 2 * y2 + (sub >> 1), ix = 2 * x2 + (sub & 1);
  bool valid = active && iy < HIN && ix < HIN;
  const float* base = U + ((long)(b * C + c) * HIN + iy) * HIN + ix;
  bool writer = active && (sub == 0);
  float* op = out + mm;
  IIR si, so;
  for (int t = 0; t < TT; ++t) {
    float a = valid ? base[(long)t * SIN] : 0.f;
    float s = si.step(a);
    float v = s + __shfl_xor(s, 1);
    v = v + __shfl_xor(v, 2);
    float o = so.step(11.0f * v);
    if (writer) op[(long)t * NOUT] = o;
  }
}

// ---------------- psp+spike, time-major, IN-PLACE (small layers) ----------------
__global__ __launch_bounds__(256) void psp_spike_tm(float* __restrict__ io, int N) {
  int n = blockIdx.x * 256 + threadIdx.x;
  if (n >= N) return;
  IIR st;
  for (int t = 0; t < TT; ++t) {
    long idx = (long)t * N + n;
    io[idx] = st.step(io[idx]);
  }
}

// ---------------- dense7 sparse: U[row][o] = sum_k S[row][k]*Wt[k][o] ----------------
// S rows are 0/1 spikes: skip zero terms (bit-exact; ascending-k order kept).
// One wave per row; lane covers 4 outputs.
__global__ __launch_bounds__(256) void dense7s(const float* __restrict__ S,
                                               const float* __restrict__ Wt,
                                               float* __restrict__ U) {
  int wave = (blockIdx.x * 256 + threadIdx.x) >> 6;  // 0..1199
  int lane = threadIdx.x & 63;
  const float* sr = S + (long)wave * 2400;
  const float* wbase = Wt + lane * 4;
  float4 acc = {0.f, 0.f, 0.f, 0.f};
  for (int k0 = 0; k0 < 2400; k0 += 64) {
    int k = k0 + lane;
    float v = (k < 2400) ? sr[k] : 0.f;
    unsigned long long msk = __ballot(v != 0.f);
    while (msk) {
      int bb = __ffsll((unsigned long long)msk) - 1;
      msk &= msk - 1;
      float4 w = *(const float4*)(wbase + (long)(k0 + bb) * 256);
      acc.x += w.x; acc.y += w.y; acc.z += w.z; acc.w += w.w;
    }
  }
  *(float4*)(U + (long)wave * 256 + lane * 4) = acc;
}

// ---------------- dense8, float4-vectorized (same ascending-k order) ----------------
__global__ __launch_bounds__(256) void dense8(const float* __restrict__ S,
                                              const float* __restrict__ W,
                                              float* __restrict__ U) {
  int id = blockIdx.x * 256 + threadIdx.x;
  if (id >= 12000) return;
  int o = id % 10, row = id / 10;
  const float* sr = S + (long)row * 256;
  const float* wr = W + o * 256;
  float acc = 0.f;
  for (int k = 0; k < 256; k += 4) {
    float4 a = *(const float4*)(sr + k);
    float4 w = *(const float4*)(wr + k);
    acc += a.x * w.x; acc += a.y * w.y; acc += a.z * w.z; acc += a.w * w.w;
  }
  U[id] = acc;
}

// ---------------- final psp+spike + transpose to (B,10,T) ----------------
__global__ void psp8_out(const float* __restrict__ U, float* __restrict__ out) {
  int n = threadIdx.x;
  if (n >= 40) return;
  IIR st;
  for (int t = 0; t < TT; ++t) out[n * TT + t] = st.step(U[t * 40 + n]);
}

extern "C" void kernel_launch(void* const* d_in, const int* in_sizes, int n_in,
                              void* d_out, int out_size, void* d_ws, size_t ws_size,
                              hipStream_t stream) {
  const float* s_in = (const float*)d_in[0];
  const float* Wc1  = (const float*)d_in[1];
  const float* Wc2  = (const float*)d_in[2];
  const float* Wc3  = (const float*)d_in[3];
  const float* Wd4a = (const float*)d_in[4];
  const float* Wd4b = (const float*)d_in[5];

  float* Buf1 = (float*)d_ws;            // 33,292,800 floats (U1/U3/U5)
  float* Buf2 = Buf1 + 33292800;
  float* s2   = Buf2;                    //  8,323,200
  float* s4   = Buf2 + 8323200;          //  4,665,600
  float* Wt4a = Buf2 + 12988800;         //    614,400
  float* U7   = Buf2 + 13603200;         //    307,200 (becomes s7 in-place)
  float* T0   = Buf2 + 13910400;         //  2,774,400
  float* Wt1  = Buf2 + 16684800;         //      1,200
  float* Wt2  = Buf2 + 16686000;         //     10,368
  float* Wt3  = Buf2 + 16696368;         //     41,472
  float* s6   = Buf2;                    //  2,880,000 (s2 region, dead by L6)
  float* U8   = Buf1;                    //     12,000 (Buf1 dead by L8)

  // prep: input -> time-major; Wd4a -> [k][o]; conv weights -> [k][co]
  transpose_rc<<<dim3(5, 145), 256, 0, stream>>>(s_in, T0, 9248, 300);
  transpose_rc<<<dim3(38, 4), 256, 0, stream>>>(Wd4a, Wt4a, 256, 2400);
  prep_w<<<208, 256, 0, stream>>>(Wc1, Wc2, Wc3, Wt1, Wt2, Wt3);

  // L1: conv 2->24 k5 p2 (NCO=6, NPX=4, RS=39, NITER=5)
  conv_tm4<2, 34, 5, 2, 24, 6, 4, 39, 5><<<dim3(300, 4, 1), 256, 0, stream>>>(T0, Wt1, Buf1);
  // L1-psp + pool 34->17 + psp -> s2   (4 lanes per pooled neuron)
  ppp4_tm<24, 34, 17><<<434, 256, 0, stream>>>(Buf1, s2, 4);
  // L3: conv 24->48 k3 p1 (NCO=12, NPX=6, RS=19, NITER=1)
  conv_tm4<24, 17, 3, 1, 48, 12, 6, 19, 1><<<dim3(300, 4, 1), 256, 0, stream>>>(s2, Wt2, Buf1);
  // L3-psp + pool 17->9 + psp -> s4
  ppp4_tm<48, 17, 9><<<243, 256, 0, stream>>>(Buf1, s4, 4);
  // L5: conv 48->96 k3 p1 (NCO=24, NPX=2, RS=13, NITER=1, single channel group)
  conv_tm4<48, 9, 3, 1, 96, 24, 2, 13, 1><<<dim3(300, 4, 1), 256, 0, stream>>>(s4, Wt3, Buf1);
  // L5-psp + pool 9->5 + psp -> s6
  ppp4_tm<96, 9, 5><<<150, 256, 0, stream>>>(Buf1, s6, 4);
  // L7: dense 2400->256 (ballot-sparse) ; psp in place
  dense7s<<<300, 256, 0, stream>>>(s6, Wt4a, U7);
  psp_spike_tm<<<4, 256, 0, stream>>>(U7, 1024);
  // L8: dense 256->10 ; psp + output transpose
  dense8<<<47, 256, 0, stream>>>(U7, Wd4b, U8);
  psp8_out<<<1, 64, 0, stream>>>(U8, (float*)d_out);
}

// Round 6
// 942.960 us; speedup vs baseline: 1.1420x; 1.1420x over previous
//
#include <hip/hip_runtime.h>

// SLAYER SNN forward, round 6.
// - time-major [t][b][c][h][w].
// - conv_tm5: odd LDS row strides, SGPR weights, register window; px-pairs
//   expressed as 2-wide vector ops so LLVM can emit v_pk_fma_f32 (chains per
//   output unchanged -> bit-exact).
// - dense7r: register-blocked dense GEMM, 1 wave = 4 rows x 256 outs,
//   ascending-k scalar chain per output (bit-exact), packed across rows.
// - ppp4_tm: fused psp->pool->psp, 4 lanes per pooled neuron.
// All fp32; IIR op ordering bit-matches the reference scan.

#define TT 300

#define A1 0.9048374180359595f   // exp(-1/10)
#define C1 0.2718281828459045f   // e/10
#define A2 0.36787944117144233f  // exp(-1)
#define C2 2.718281828459045f    // e
#define KREF (20.0f * C2)
#define THETA_F 10.0f

typedef float v2f __attribute__((ext_vector_type(2)));

struct IIR {
  float p1, q1, p2, q2;
  __device__ IIR() : p1(0.f), q1(0.f), p2(0.f), q2(0.f) {}
  __device__ inline float step(float xin) {
    q1 = A1 * q1 + A1 * p1;
    float y = C1 * q1;
    p1 = A1 * p1 + xin;
    q2 = A2 * q2 + A2 * p2;
    float u = y - KREF * q2;
    float s = (u >= THETA_F) ? 1.0f : 0.0f;
    p2 = A2 * p2 + s;
    return s;
  }
};

// ---------------- generic tiled transpose: in[R][C] -> out[C][R] ----------------
__global__ __launch_bounds__(256) void transpose_rc(const float* __restrict__ in,
                                                    float* __restrict__ out,
                                                    int R, int C) {
  __shared__ float tile[64][65];
  int c0 = blockIdx.x * 64, r0 = blockIdx.y * 64;
  int tx = threadIdx.x & 63, ty = threadIdx.x >> 6;
  for (int i = ty; i < 64; i += 4) {
    int r = r0 + i, c = c0 + tx;
    if (r < R && c < C) tile[i][tx] = in[(long)r * C + c];
  }
  __syncthreads();
  for (int i = ty; i < 64; i += 4) {
    int c = c0 + i, r = r0 + tx;
    if (c < C && r < R) out[(long)c * R + r] = tile[tx][i];
  }
}

// ---------------- conv-weight transposes, one launch ----------------
__global__ __launch_bounds__(256) void prep_w(const float* __restrict__ Wc1,
                                              const float* __restrict__ Wc2,
                                              const float* __restrict__ Wc3,
                                              float* __restrict__ Wt1,
                                              float* __restrict__ Wt2,
                                              float* __restrict__ Wt3) {
  int i = blockIdx.x * 256 + threadIdx.x;
  if (i < 1200) { int co = i / 50, k = i % 50; Wt1[k * 24 + co] = Wc1[i]; return; }
  i -= 1200;
  if (i < 10368) { int co = i / 216, k = i % 216; Wt2[k * 48 + co] = Wc2[i]; return; }
  i -= 10368;
  if (i < 41472) { int co = i / 432, k = i % 432; Wt3[k * 96 + co] = Wc3[i]; }
}

// ---------------- per-timestep conv, time-major ----------------
// S: [T][B][CIN][HW][HW], Wt: [CIN][KS][KS][CO], U: [T][B][CO][HW][HW]
// 4 waves/block; wave w -> channels [z*4*NCO + w*NCO, +NCO); lane -> (y, x-group).
// NPX must be even: px-pairs run as v2f so LLVM can pack fp32 FMAs.
template <int CIN, int HW, int KS, int PAD, int CO, int NCO, int NPX, int RS, int NITER>
__global__ __launch_bounds__(256) void conv_tm5(const float* __restrict__ S,
                                                const float* __restrict__ Wt,
                                                float* __restrict__ U) {
  constexpr int PH = HW + 2 * PAD;
  constexpr int TILE = CIN * PH * RS;
  constexpr int XG = (HW + NPX - 1) / NPX;
  constexpr int SLOTS = HW * XG;
  constexpr int WIN = NPX + KS - 1;
  constexpr int NP2 = NPX / 2;
  __shared__ float lin[TILE + WIN];
  const int t = blockIdx.x, b = blockIdx.y, B = gridDim.y;

  for (int i = threadIdx.x; i < TILE + WIN; i += 256) lin[i] = 0.f;
  __syncthreads();
  const float* src = S + ((long)t * B + b) * (CIN * HW * HW);
  for (int i = threadIdx.x; i < CIN * HW * HW; i += 256) {
    int ci = i / (HW * HW), r = i % (HW * HW);
    int iy = r / HW, ix = r % HW;
    lin[ci * PH * RS + (iy + PAD) * RS + ix + PAD] = src[i];
  }
  __syncthreads();

  const int lane = threadIdx.x & 63;
  const int co0 = blockIdx.z * (4 * NCO) +
                  __builtin_amdgcn_readfirstlane(threadIdx.x >> 6) * NCO;
  const float* wb = Wt + co0;

  for (int it = 0; it < NITER; ++it) {
    int slot = lane + 64 * it;
    bool act = slot < SLOTS;
    int ss = act ? slot : 0;
    int y = ss / XG, x0 = (ss % XG) * NPX;
    const float* base = lin + y * RS + x0;
    v2f acc[NCO][NP2];
#pragma unroll
    for (int j = 0; j < NCO; ++j)
#pragma unroll
      for (int p = 0; p < NP2; ++p) acc[j][p] = (v2f)(0.f);

    for (int ci = 0; ci < CIN; ++ci) {
      const float* bp = base + ci * (PH * RS);
#pragma unroll
      for (int dy = 0; dy < KS; ++dy) {
        float win[WIN];
#pragma unroll
        for (int k = 0; k < WIN; ++k) win[k] = bp[dy * RS + k];
#pragma unroll
        for (int dx = 0; dx < KS; ++dx) {
          float wv[NCO];
#pragma unroll
          for (int j = 0; j < NCO; ++j)
            wv[j] = wb[(((ci * KS + dy) * KS + dx) * CO) + j];
#pragma unroll
          for (int p = 0; p < NP2; ++p) {
            v2f wpair;
            wpair.x = win[2 * p + dx];
            wpair.y = win[2 * p + 1 + dx];
#pragma unroll
            for (int j = 0; j < NCO; ++j)
              acc[j][p] += wpair * wv[j];
          }
        }
      }
    }
    if (act) {
      float* up = U + (((long)t * B + b) * CO + co0) * (HW * HW) + y * HW + x0;
#pragma unroll
      for (int j = 0; j < NCO; ++j)
#pragma unroll
        for (int p = 0; p < NP2; ++p) {
          if (x0 + 2 * p < HW) up[j * (HW * HW) + 2 * p] = acc[j][p].x;
          if (x0 + 2 * p + 1 < HW) up[j * (HW * HW) + 2 * p + 1] = acc[j][p].y;
        }
    }
  }
}

// ---------------- fused psp+spike -> pool(2x2, x11) -> psp+spike, 4 lanes/neuron ----------------
template <int C, int HIN, int HOUT>
__global__ __launch_bounds__(256) void ppp4_tm(const float* __restrict__ U,
                                               float* __restrict__ out, int B) {
  const int NOUT = B * C * HOUT * HOUT;
  const long SIN = (long)B * C * HIN * HIN;
  int id = blockIdx.x * 256 + threadIdx.x;
  int sub = id & 3, m = id >> 2;
  bool active = m < NOUT;
  int mm = active ? m : 0;
  int x2 = mm % HOUT;
  int y2 = (mm / HOUT) % HOUT;
  int c = (mm / (HOUT * HOUT)) % C;
  int b = mm / (C * HOUT * HOUT);
  int iy = 2 * y2 + (sub >> 1), ix = 2 * x2 + (sub & 1);
  bool valid = active && iy < HIN && ix < HIN;
  const float* base = U + ((long)(b * C + c) * HIN + iy) * HIN + ix;
  bool writer = active && (sub == 0);
  float* op = out + mm;
  IIR si, so;
  for (int t = 0; t < TT; ++t) {
    float a = valid ? base[(long)t * SIN] : 0.f;
    float s = si.step(a);
    float v = s + __shfl_xor(s, 1);
    v = v + __shfl_xor(v, 2);
    float o = so.step(11.0f * v);
    if (writer) op[(long)t * NOUT] = o;
  }
}

// ---------------- psp+spike, time-major, out-of-place ----------------
__global__ __launch_bounds__(256) void psp_spike_tm2(const float* __restrict__ in,
                                                     float* __restrict__ out, int N) {
  int n = blockIdx.x * 256 + threadIdx.x;
  if (n >= N) return;
  IIR st;
  for (int t = 0; t < TT; ++t) {
    long idx = (long)t * N + n;
    out[idx] = st.step(in[idx]);
  }
}

// ---------------- dense7r: U[row][o] = sum_k S[row][k]*Wt[k][o], reg-blocked ----------------
// 1 wave (64-thread block) = 4 rows x 256 outputs; lane -> 4 outputs.
// Each output is one ascending-k fp32 chain (bit-exact); rows packed as v2f.
__global__ __launch_bounds__(64) void dense7r(const float* __restrict__ S,
                                              const float* __restrict__ Wt,
                                              float* __restrict__ U) {
  const int r0 = blockIdx.x * 4;      // 300 blocks
  const int lane = threadIdx.x;
  const float* s0 = S + (long)r0 * 2400;
  const float* s1 = s0 + 2400;
  const float* s2 = s0 + 4800;
  const float* s3 = s0 + 7200;
  const float* wp = Wt + lane * 4;
  v2f aA[4], aB[4];  // rows {0,1} and {2,3}, outputs 0..3
#pragma unroll
  for (int o = 0; o < 4; ++o) { aA[o] = (v2f)(0.f); aB[o] = (v2f)(0.f); }
  for (int k = 0; k < 2400; k += 4) {
    float4 a0 = *(const float4*)(s0 + k);
    float4 a1 = *(const float4*)(s1 + k);
    float4 a2 = *(const float4*)(s2 + k);
    float4 a3 = *(const float4*)(s3 + k);
#define DSTEP(KK, AX)                                                        \
    {                                                                        \
      float4 w = *(const float4*)(wp + (long)(k + KK) * 256);                \
      v2f pA, pB;                                                            \
      pA.x = a0.AX; pA.y = a1.AX; pB.x = a2.AX; pB.y = a3.AX;                \
      aA[0] += pA * w.x; aA[1] += pA * w.y; aA[2] += pA * w.z; aA[3] += pA * w.w; \
      aB[0] += pB * w.x; aB[1] += pB * w.y; aB[2] += pB * w.z; aB[3] += pB * w.w; \
    }
    DSTEP(0, x) DSTEP(1, y) DSTEP(2, z) DSTEP(3, w)
#undef DSTEP
  }
  float* u0 = U + (long)r0 * 256 + lane * 4;
#pragma unroll
  for (int o = 0; o < 4; ++o) u0[o] = aA[o].x;
#pragma unroll
  for (int o = 0; o < 4; ++o) u0[256 + o] = aA[o].y;
#pragma unroll
  for (int o = 0; o < 4; ++o) u0[512 + o] = aB[o].x;
#pragma unroll
  for (int o = 0; o < 4; ++o) u0[768 + o] = aB[o].y;
}

// ---------------- dense8, float4-vectorized (ascending-k order) ----------------
__global__ __launch_bounds__(256) void dense8(const float* __restrict__ S,
                                              const float* __restrict__ W,
                                              float* __restrict__ U) {
  int id = blockIdx.x * 256 + threadIdx.x;
  if (id >= 12000) return;
  int o = id % 10, row = id / 10;
  const float* sr = S + (long)row * 256;
  const float* wr = W + o * 256;
  float acc = 0.f;
  for (int k = 0; k < 256; k += 4) {
    float4 a = *(const float4*)(sr + k);
    float4 w = *(const float4*)(wr + k);
    acc += a.x * w.x; acc += a.y * w.y; acc += a.z * w.z; acc += a.w * w.w;
  }
  U[id] = acc;
}

// ---------------- final psp+spike + transpose to (B,10,T) ----------------
__global__ void psp8_out(const float* __restrict__ U, float* __restrict__ out) {
  int n = threadIdx.x;
  if (n >= 40) return;
  IIR st;
  for (int t = 0; t < TT; ++t) out[n * TT + t] = st.step(U[t * 40 + n]);
}

extern "C" void kernel_launch(void* const* d_in, const int* in_sizes, int n_in,
                              void* d_out, int out_size, void* d_ws, size_t ws_size,
                              hipStream_t stream) {
  const float* s_in = (const float*)d_in[0];
  const float* Wc1  = (const float*)d_in[1];
  const float* Wc2  = (const float*)d_in[2];
  const float* Wc3  = (const float*)d_in[3];
  const float* Wd4a = (const float*)d_in[4];
  const float* Wd4b = (const float*)d_in[5];

  float* Buf1 = (float*)d_ws;            // 33,292,800 floats (U1/U3/U5)
  float* Buf2 = Buf1 + 33292800;
  float* s2   = Buf2;                    //  8,323,200
  float* s4   = Buf2 + 8323200;          //  4,665,600
  float* Wt4a = Buf2 + 12988800;         //    614,400
  float* U7   = Buf2 + 13603200;         //    307,200
  float* T0   = Buf2 + 13910400;         //  2,774,400
  float* Wt1  = Buf2 + 16684800;         //      1,200
  float* Wt2  = Buf2 + 16686000;         //     10,368
  float* Wt3  = Buf2 + 16696368;         //     41,472
  float* s7   = Buf2 + 16737840;         //    307,200
  float* s6   = Buf2;                    //  2,880,000 (s2 region, dead by L6)
  float* U8   = Buf1;                    //     12,000 (Buf1 dead by L8)

  // prep: input -> time-major; Wd4a -> [k][o]; conv weights -> [k][co]
  transpose_rc<<<dim3(5, 145), 256, 0, stream>>>(s_in, T0, 9248, 300);
  transpose_rc<<<dim3(38, 4), 256, 0, stream>>>(Wd4a, Wt4a, 256, 2400);
  prep_w<<<208, 256, 0, stream>>>(Wc1, Wc2, Wc3, Wt1, Wt2, Wt3);

  // L1: conv 2->24 k5 p2 (NCO=6, NPX=4, RS=39, NITER=5)
  conv_tm5<2, 34, 5, 2, 24, 6, 4, 39, 5><<<dim3(300, 4, 1), 256, 0, stream>>>(T0, Wt1, Buf1);
  // L1-psp + pool 34->17 + psp -> s2
  ppp4_tm<24, 34, 17><<<434, 256, 0, stream>>>(Buf1, s2, 4);
  // L3: conv 24->48 k3 p1 (NCO=12, NPX=6, RS=19, NITER=1)
  conv_tm5<24, 17, 3, 1, 48, 12, 6, 19, 1><<<dim3(300, 4, 1), 256, 0, stream>>>(s2, Wt2, Buf1);
  // L3-psp + pool 17->9 + psp -> s4
  ppp4_tm<48, 17, 9><<<243, 256, 0, stream>>>(Buf1, s4, 4);
  // L5: conv 48->96 k3 p1 (NCO=24, NPX=2, RS=13, NITER=1)
  conv_tm5<48, 9, 3, 1, 96, 24, 2, 13, 1><<<dim3(300, 4, 1), 256, 0, stream>>>(s4, Wt3, Buf1);
  // L5-psp + pool 9->5 + psp -> s6
  ppp4_tm<96, 9, 5><<<150, 256, 0, stream>>>(Buf1, s6, 4);
  // L7: dense 2400->256 (register-blocked) ; psp U7 -> s7
  dense7r<<<300, 64, 0, stream>>>(s6, Wt4a, U7);
  psp_spike_tm2<<<4, 256, 0, stream>>>(U7, s7, 1024);
  // L8: dense 256->10 ; psp + output transpose
  dense8<<<47, 256, 0, stream>>>(s7, Wd4b, U8);
  psp8_out<<<1, 64, 0, stream>>>(U8, (float*)d_out);
}

// Round 7
// 798.766 us; speedup vs baseline: 1.3481x; 1.1805x over previous
//
#include <hip/hip_runtime.h>

// SLAYER SNN forward, round 7.
// - time-major [t][b][c][h][w].
// - conv_tm5: odd LDS row strides, SGPR weights, register window, v2f packing.
// - dense7k: round-6 dense7r inner loop + SPLIT-K x4 (4x wave count, the round-6
//   failure was 0.3 waves/SIMD). Partials P[4][1200][256] in ws.
// - psp7_reduce: psp+spike for L7 with the 4-way kz reduction fused in.
// - ppp4_tm: fused psp->pool->psp, 4 lanes per pooled neuron.
// All fp32; IIR op ordering bit-matches the reference scan.

#define TT 300

#define A1 0.9048374180359595f   // exp(-1/10)
#define C1 0.2718281828459045f   // e/10
#define A2 0.36787944117144233f  // exp(-1)
#define C2 2.718281828459045f    // e
#define KREF (20.0f * C2)
#define THETA_F 10.0f

typedef float v2f __attribute__((ext_vector_type(2)));

struct IIR {
  float p1, q1, p2, q2;
  __device__ IIR() : p1(0.f), q1(0.f), p2(0.f), q2(0.f) {}
  __device__ inline float step(float xin) {
    q1 = A1 * q1 + A1 * p1;
    float y = C1 * q1;
    p1 = A1 * p1 + xin;
    q2 = A2 * q2 + A2 * p2;
    float u = y - KREF * q2;
    float s = (u >= THETA_F) ? 1.0f : 0.0f;
    p2 = A2 * p2 + s;
    return s;
  }
};

// ---------------- generic tiled transpose: in[R][C] -> out[C][R] ----------------
__global__ __launch_bounds__(256) void transpose_rc(const float* __restrict__ in,
                                                    float* __restrict__ out,
                                                    int R, int C) {
  __shared__ float tile[64][65];
  int c0 = blockIdx.x * 64, r0 = blockIdx.y * 64;
  int tx = threadIdx.x & 63, ty = threadIdx.x >> 6;
  for (int i = ty; i < 64; i += 4) {
    int r = r0 + i, c = c0 + tx;
    if (r < R && c < C) tile[i][tx] = in[(long)r * C + c];
  }
  __syncthreads();
  for (int i = ty; i < 64; i += 4) {
    int c = c0 + i, r = r0 + tx;
    if (c < C && r < R) out[(long)c * R + r] = tile[tx][i];
  }
}

// ---------------- conv-weight transposes, one launch ----------------
__global__ __launch_bounds__(256) void prep_w(const float* __restrict__ Wc1,
                                              const float* __restrict__ Wc2,
                                              const float* __restrict__ Wc3,
                                              float* __restrict__ Wt1,
                                              float* __restrict__ Wt2,
                                              float* __restrict__ Wt3) {
  int i = blockIdx.x * 256 + threadIdx.x;
  if (i < 1200) { int co = i / 50, k = i % 50; Wt1[k * 24 + co] = Wc1[i]; return; }
  i -= 1200;
  if (i < 10368) { int co = i / 216, k = i % 216; Wt2[k * 48 + co] = Wc2[i]; return; }
  i -= 10368;
  if (i < 41472) { int co = i / 432, k = i % 432; Wt3[k * 96 + co] = Wc3[i]; }
}

// ---------------- per-timestep conv, time-major ----------------
template <int CIN, int HW, int KS, int PAD, int CO, int NCO, int NPX, int RS, int NITER>
__global__ __launch_bounds__(256) void conv_tm5(const float* __restrict__ S,
                                                const float* __restrict__ Wt,
                                                float* __restrict__ U) {
  constexpr int PH = HW + 2 * PAD;
  constexpr int TILE = CIN * PH * RS;
  constexpr int XG = (HW + NPX - 1) / NPX;
  constexpr int SLOTS = HW * XG;
  constexpr int WIN = NPX + KS - 1;
  constexpr int NP2 = NPX / 2;
  __shared__ float lin[TILE + WIN];
  const int t = blockIdx.x, b = blockIdx.y, B = gridDim.y;

  for (int i = threadIdx.x; i < TILE + WIN; i += 256) lin[i] = 0.f;
  __syncthreads();
  const float* src = S + ((long)t * B + b) * (CIN * HW * HW);
  for (int i = threadIdx.x; i < CIN * HW * HW; i += 256) {
    int ci = i / (HW * HW), r = i % (HW * HW);
    int iy = r / HW, ix = r % HW;
    lin[ci * PH * RS + (iy + PAD) * RS + ix + PAD] = src[i];
  }
  __syncthreads();

  const int lane = threadIdx.x & 63;
  const int co0 = blockIdx.z * (4 * NCO) +
                  __builtin_amdgcn_readfirstlane(threadIdx.x >> 6) * NCO;
  const float* wb = Wt + co0;

  for (int it = 0; it < NITER; ++it) {
    int slot = lane + 64 * it;
    bool act = slot < SLOTS;
    int ss = act ? slot : 0;
    int y = ss / XG, x0 = (ss % XG) * NPX;
    const float* base = lin + y * RS + x0;
    v2f acc[NCO][NP2];
#pragma unroll
    for (int j = 0; j < NCO; ++j)
#pragma unroll
      for (int p = 0; p < NP2; ++p) acc[j][p] = (v2f)(0.f);

    for (int ci = 0; ci < CIN; ++ci) {
      const float* bp = base + ci * (PH * RS);
#pragma unroll
      for (int dy = 0; dy < KS; ++dy) {
        float win[WIN];
#pragma unroll
        for (int k = 0; k < WIN; ++k) win[k] = bp[dy * RS + k];
#pragma unroll
        for (int dx = 0; dx < KS; ++dx) {
          float wv[NCO];
#pragma unroll
          for (int j = 0; j < NCO; ++j)
            wv[j] = wb[(((ci * KS + dy) * KS + dx) * CO) + j];
#pragma unroll
          for (int p = 0; p < NP2; ++p) {
            v2f wpair;
            wpair.x = win[2 * p + dx];
            wpair.y = win[2 * p + 1 + dx];
#pragma unroll
            for (int j = 0; j < NCO; ++j)
              acc[j][p] += wpair * wv[j];
          }
        }
      }
    }
    if (act) {
      float* up = U + (((long)t * B + b) * CO + co0) * (HW * HW) + y * HW + x0;
#pragma unroll
      for (int j = 0; j < NCO; ++j)
#pragma unroll
        for (int p = 0; p < NP2; ++p) {
          if (x0 + 2 * p < HW) up[j * (HW * HW) + 2 * p] = acc[j][p].x;
          if (x0 + 2 * p + 1 < HW) up[j * (HW * HW) + 2 * p + 1] = acc[j][p].y;
        }
    }
  }
}

// ---------------- fused psp+spike -> pool(2x2, x11) -> psp+spike, 4 lanes/neuron ----------------
template <int C, int HIN, int HOUT>
__global__ __launch_bounds__(256) void ppp4_tm(const float* __restrict__ U,
                                               float* __restrict__ out, int B) {
  const int NOUT = B * C * HOUT * HOUT;
  const long SIN = (long)B * C * HIN * HIN;
  int id = blockIdx.x * 256 + threadIdx.x;
  int sub = id & 3, m = id >> 2;
  bool active = m < NOUT;
  int mm = active ? m : 0;
  int x2 = mm % HOUT;
  int y2 = (mm / HOUT) % HOUT;
  int c = (mm / (HOUT * HOUT)) % C;
  int b = mm / (C * HOUT * HOUT);
  int iy = 2 * y2 + (sub >> 1), ix = 2 * x2 + (sub & 1);
  bool valid = active && iy < HIN && ix < HIN;
  const float* base = U + ((long)(b * C + c) * HIN + iy) * HIN + ix;
  bool writer = active && (sub == 0);
  float* op = out + mm;
  IIR si, so;
  for (int t = 0; t < TT; ++t) {
    float a = valid ? base[(long)t * SIN] : 0.f;
    float s = si.step(a);
    float v = s + __shfl_xor(s, 1);
    v = v + __shfl_xor(v, 2);
    float o = so.step(11.0f * v);
    if (writer) op[(long)t * NOUT] = o;
  }
}

// ---------------- dense7k: split-k GEMM, P[kz][row][o] partials ----------------
// 1 wave = 4 rows x 256 outs over k-chunk of 600; lane -> 4 outs; v2f row pairs.
// Grid (75, 4): bx -> 16 rows (4 waves), by = kz.
__global__ __launch_bounds__(256) void dense7k(const float* __restrict__ S,
                                               const float* __restrict__ Wt,
                                               float* __restrict__ P) {
  const int r0 = blockIdx.x * 16 + (threadIdx.x >> 6) * 4;
  const int kz = blockIdx.y;
  const int lane = threadIdx.x & 63;
  const float* s0 = S + (long)r0 * 2400;
  const float* s1 = s0 + 2400;
  const float* s2 = s0 + 4800;
  const float* s3 = s0 + 7200;
  const float* wp = Wt + lane * 4;
  v2f aA[4], aB[4];
#pragma unroll
  for (int o = 0; o < 4; ++o) { aA[o] = (v2f)(0.f); aB[o] = (v2f)(0.f); }
  const int k0 = kz * 600, k1 = k0 + 600;
  for (int k = k0; k < k1; k += 4) {
    float4 a0 = *(const float4*)(s0 + k);
    float4 a1 = *(const float4*)(s1 + k);
    float4 a2 = *(const float4*)(s2 + k);
    float4 a3 = *(const float4*)(s3 + k);
#define DSTEP(KK, AX)                                                        \
    {                                                                        \
      float4 w = *(const float4*)(wp + (long)(k + KK) * 256);                \
      v2f pA, pB;                                                            \
      pA.x = a0.AX; pA.y = a1.AX; pB.x = a2.AX; pB.y = a3.AX;                \
      aA[0] += pA * w.x; aA[1] += pA * w.y; aA[2] += pA * w.z; aA[3] += pA * w.w; \
      aB[0] += pB * w.x; aB[1] += pB * w.y; aB[2] += pB * w.z; aB[3] += pB * w.w; \
    }
    DSTEP(0, x) DSTEP(1, y) DSTEP(2, z) DSTEP(3, w)
#undef DSTEP
  }
  float* p = P + (long)kz * 307200 + (long)r0 * 256 + lane * 4;
#pragma unroll
  for (int o = 0; o < 4; ++o) p[o] = aA[o].x;
#pragma unroll
  for (int o = 0; o < 4; ++o) p[256 + o] = aA[o].y;
#pragma unroll
  for (int o = 0; o < 4; ++o) p[512 + o] = aB[o].x;
#pragma unroll
  for (int o = 0; o < 4; ++o) p[768 + o] = aB[o].y;
}

// ---------------- psp+spike for L7 with fused 4-way kz reduction ----------------
// P: [4][300*4][256] = [4][t*4+b][o]; out s7: [t*4+b][o] spikes (n = b*256+o contiguous).
__global__ __launch_bounds__(256) void psp7_reduce(const float* __restrict__ P,
                                                   float* __restrict__ out) {
  int n = blockIdx.x * 256 + threadIdx.x;  // 0..1023
  IIR st;
  for (int t = 0; t < TT; ++t) {
    long idx = (long)t * 1024 + n;
    float u = ((P[idx] + P[307200 + idx]) + P[614400 + idx]) + P[921600 + idx];
    out[idx] = st.step(u);
  }
}

// ---------------- dense8, float4-vectorized (ascending-k order) ----------------
__global__ __launch_bounds__(256) void dense8(const float* __restrict__ S,
                                              const float* __restrict__ W,
                                              float* __restrict__ U) {
  int id = blockIdx.x * 256 + threadIdx.x;
  if (id >= 12000) return;
  int o = id % 10, row = id / 10;
  const float* sr = S + (long)row * 256;
  const float* wr = W + o * 256;
  float acc = 0.f;
  for (int k = 0; k < 256; k += 4) {
    float4 a = *(const float4*)(sr + k);
    float4 w = *(const float4*)(wr + k);
    acc += a.x * w.x; acc += a.y * w.y; acc += a.z * w.z; acc += a.w * w.w;
  }
  U[id] = acc;
}

// ---------------- final psp+spike + transpose to (B,10,T) ----------------
__global__ void psp8_out(const float* __restrict__ U, float* __restrict__ out) {
  int n = threadIdx.x;
  if (n >= 40) return;
  IIR st;
  for (int t = 0; t < TT; ++t) out[n * TT + t] = st.step(U[t * 40 + n]);
}

extern "C" void kernel_launch(void* const* d_in, const int* in_sizes, int n_in,
                              void* d_out, int out_size, void* d_ws, size_t ws_size,
                              hipStream_t stream) {
  const float* s_in = (const float*)d_in[0];
  const float* Wc1  = (const float*)d_in[1];
  const float* Wc2  = (const float*)d_in[2];
  const float* Wc3  = (const float*)d_in[3];
  const float* Wd4a = (const float*)d_in[4];
  const float* Wd4b = (const float*)d_in[5];

  float* Buf1 = (float*)d_ws;            // 33,292,800 floats (U1/U3/U5)
  float* Buf2 = Buf1 + 33292800;
  float* s2   = Buf2;                    //  8,323,200
  float* s4   = Buf2 + 8323200;          //  4,665,600
  float* Wt4a = Buf2 + 12988800;         //    614,400
  float* T0   = Buf2 + 13910400;         //  2,774,400
  float* Wt1  = Buf2 + 16684800;         //      1,200
  float* Wt2  = Buf2 + 16686000;         //     10,368
  float* Wt3  = Buf2 + 16696368;         //     41,472
  float* s7   = Buf2 + 16737840;         //    307,200
  float* P7   = Buf2 + 17045040;         //  1,228,800 (4 x 307,200 partials)
  float* s6   = Buf2;                    //  2,880,000 (s2 region, dead by L6)
  float* U8   = Buf1;                    //     12,000 (Buf1 dead by L8)

  // prep: input -> time-major; Wd4a -> [k][o]; conv weights -> [k][co]
  transpose_rc<<<dim3(5, 145), 256, 0, stream>>>(s_in, T0, 9248, 300);
  transpose_rc<<<dim3(38, 4), 256, 0, stream>>>(Wd4a, Wt4a, 256, 2400);
  prep_w<<<208, 256, 0, stream>>>(Wc1, Wc2, Wc3, Wt1, Wt2, Wt3);

  // L1: conv 2->24 k5 p2 (NCO=6, NPX=4, RS=39, NITER=5)
  conv_tm5<2, 34, 5, 2, 24, 6, 4, 39, 5><<<dim3(300, 4, 1), 256, 0, stream>>>(T0, Wt1, Buf1);
  // L1-psp + pool 34->17 + psp -> s2
  ppp4_tm<24, 34, 17><<<434, 256, 0, stream>>>(Buf1, s2, 4);
  // L3: conv 24->48 k3 p1 (NCO=12, NPX=6, RS=19, NITER=1)
  conv_tm5<24, 17, 3, 1, 48, 12, 6, 19, 1><<<dim3(300, 4, 1), 256, 0, stream>>>(s2, Wt2, Buf1);
  // L3-psp + pool 17->9 + psp -> s4
  ppp4_tm<48, 17, 9><<<243, 256, 0, stream>>>(Buf1, s4, 4);
  // L5: conv 48->96 k3 p1 (NCO=24, NPX=2, RS=13, NITER=1)
  conv_tm5<48, 9, 3, 1, 96, 24, 2, 13, 1><<<dim3(300, 4, 1), 256, 0, stream>>>(s4, Wt3, Buf1);
  // L5-psp + pool 9->5 + psp -> s6
  ppp4_tm<96, 9, 5><<<150, 256, 0, stream>>>(Buf1, s6, 4);
  // L7: dense 2400->256 split-k x4 ; psp with fused reduction -> s7
  dense7k<<<dim3(75, 4), 256, 0, stream>>>(s6, Wt4a, P7);
  psp7_reduce<<<4, 256, 0, stream>>>(P7, s7);
  // L8: dense 256->10 ; psp + output transpose
  dense8<<<47, 256, 0, stream>>>(s7, Wd4b, U8);
  psp8_out<<<1, 64, 0, stream>>>(U8, (float*)d_out);
}